// Round 1
// baseline (114.790 us; speedup 1.0000x reference)
//
#include <hip/hip_runtime.h>
#include <math.h>

#define NPART 4096

// Constants, rounded exactly as the reference's weak-typed doubles -> f32
constexpr float RORC   = (float)(2.5e-5 + 3.15e-6);    // RO + RC
constexpr float RORC2  = RORC * RORC;
constexpr float RRF    = 8e-6f;                        // RR
constexpr float RR2    = RRF * RRF;
constexpr float TWORC  = (float)(2.0 * 3.15e-6);       // 2*RC
constexpr float TWORC2 = TWORC * TWORC;
constexpr float C21RC  = (float)(2.1 * 3.15e-6);       // 2.1*RC
constexpr float C_ROT  = (float)(0.2 * 25.0 * 0.0028); // dt*Gamma*DR
constexpr float C_RN1  = (float)0.07483314773547883;   // f32(sqrt(2*DR))
constexpr float C_SQDT = (float)0.4472135954999579;    // f32(sqrt(dt))
constexpr float C_TRV  = (float)(0.2 * 5e-7);          // dt*velocity
constexpr float C_HALF = (float)0.7071067811865476;    // f32(sqrt(0.5))
constexpr float C_SQ2T = (float)1.6733200530681511e-07;// f32(sqrt(2*DT_TRANS))
constexpr float EPSF   = 1e-14f;

// ---------------------------------------------------------------------------
// Pairwise kernel: per-i { n_r, sum_rr(p), orientation_sums(u) }.
// Grid 512 blocks x 256 thr. Block owns 8 i's; 32 j-segments of 128 each.
// All (p,u) staged in 64KB LDS; reduction scratch aliases the (dead) stage.
// ---------------------------------------------------------------------------
__global__ __launch_bounds__(256) void pair_kernel(
        const float2* __restrict__ pos, const float2* __restrict__ ori,
        float* __restrict__ ws5) {
    __shared__ float4 pu[NPART];          // 64 KB
    float* red = (float*)pu;              // reused after j-loop

    const int tid = threadIdx.x;
    for (int k = 0; k < NPART / 256; ++k) {
        const int j = k * 256 + tid;
        const float2 pj = pos[j];
        const float2 uj = ori[j];
        pu[j] = make_float4(pj.x, pj.y, uj.x, uj.y);
    }
    __syncthreads();

    const int il  = tid & 7;              // i within block
    const int seg = tid >> 3;             // 0..31
    const int i   = blockIdx.x * 8 + il;
    const float pix = pu[i].x, piy = pu[i].y;

    float nr = 0.f, sx = 0.f, sy = 0.f, ox = 0.f, oy = 0.f;
    const int base = seg * 128;
    #pragma unroll 4
    for (int t = 0; t < 128; ++t) {
        const int j = base + ((t + seg) & 127);   // stagger: distinct bank groups
        const float4 v = pu[j];
        const float dx = v.x - pix, dy = v.y - piy;
        const float r2 = fmaf(dx, dx, dy * dy);
        const bool oc = (r2 <= RORC2);            // inside_Ro (diag included)
        ox += oc ? v.z : 0.f;
        oy += oc ? v.w : 0.f;
        if (r2 <= RR2) {                          // rare (~0.01% of pairs)
            // in_front fails <=> angle(dir)-angle(u_j) wrapped in [pi/2, pi)
            // <=> dot<=0 && cross>=0 (diag auto-fails: dot=cross=0)
            const float dt_ = fmaf(dx, v.z, dy * v.w);
            const float cr_ = fmaf(dy, v.z, -dx * v.w);
            const bool fail = (dt_ <= 0.f) && (cr_ >= 0.f);
            if (r2 > 0.f && !fail) { nr += 1.f; sx += v.x; sy += v.y; }
        }
    }
    __syncthreads();                       // all pu reads done before aliasing
    red[0 * 256 + tid] = nr;
    red[1 * 256 + tid] = sx;
    red[2 * 256 + tid] = sy;
    red[3 * 256 + tid] = ox;
    red[4 * 256 + tid] = oy;
    __syncthreads();
    if (tid < 40) {
        const int q = tid >> 3, ii = tid & 7;
        float acc = 0.f;
        #pragma unroll
        for (int s = 0; s < 32; ++s) acc += red[q * 256 + ii + 8 * s];
        ws5[q * NPART + blockIdx.x * 8 + ii] = acc;
    }
}

// ---------------------------------------------------------------------------
// Per-particle epilogue: mean(p), S/d, Ps, turns, cossim choice, rotation,
// translation. Writes out sections 1..4 and pos0 (collision input).
// ---------------------------------------------------------------------------
__global__ __launch_bounds__(256) void epilogue_kernel(
        const float2* __restrict__ pos, const float2* __restrict__ ori,
        const float* __restrict__ Deltas, const float* __restrict__ rot_noise,
        const float2* __restrict__ trans_noise, const float* __restrict__ ws5,
        float2* __restrict__ out, float2* __restrict__ pos0) {
    __shared__ float sredx[256], sredy[256];
    const int tid = threadIdx.x;
    const int i = blockIdx.x * 256 + tid;

    // block-wide mean of all positions (n_a == N: mask_ra is all-true)
    float mx = 0.f, my = 0.f;
    for (int k = 0; k < NPART / 256; ++k) {
        const float2 pp = pos[k * 256 + tid];
        mx += pp.x; my += pp.y;
    }
    sredx[tid] = mx; sredy[tid] = my;
    __syncthreads();
    for (int s = 128; s > 0; s >>= 1) {
        if (tid < s) { sredx[tid] += sredx[tid + s]; sredy[tid] += sredy[tid + s]; }
        __syncthreads();
    }
    const float cmx = sredx[0] * (1.f / NPART);
    const float cmy = sredy[0] * (1.f / NPART);

    const float2 p = pos[i];
    const float2 u = ori[i];
    const float nr  = ws5[0 * NPART + i];
    const float sxv = ws5[1 * NPART + i];
    const float syv = ws5[2 * NPART + i];
    const float osx = ws5[3 * NPART + i];
    const float osy = ws5[4 * NPART + i];

    const float inv = 1.f / fmaxf(nr, 1.f);
    const float sg  = (nr > 0.f) ? 1.f : 0.f;
    const float Sx = sxv * inv - p.x * sg;
    const float Sy = syv * inv - p.y * sg;
    const float dxv = -Sx, dyv = -Sy;      // d = -S

    const float Psx = cmx - p.x;           // sign(n_a)=1
    const float Psy = cmy - p.y;

    float sd, cd;
    sincosf(Deltas[0], &sd, &cd);
    const float Lx = Psx * cd - Psy * sd;  // Ps * exp(+i*Delta)
    const float Ly = Psx * sd + Psy * cd;
    const float Rx = Psx * cd + Psy * sd;  // Ps * exp(-i*Delta)
    const float Ry = Psy * cd - Psx * sd;

    const float no  = fmaxf(sqrtf(osx*osx + osy*osy + 1e-30f), EPSF);
    const float nl  = fmaxf(sqrtf(Lx*Lx + Ly*Ly + 1e-30f), EPSF);
    const float nrr = fmaxf(sqrtf(Rx*Rx + Ry*Ry + 1e-30f), EPSF);
    const float csl = (Lx * osx + Ly * osy) / (nl * no);
    const float csr = (Rx * osx + Ry * osy) / (nrr * no);
    const bool left = (csl >= csr);
    const float bx = left ? Lx : Rx;
    const float by = left ? Ly : Ry;

    float cx, cy;                          // chosen target vector
    if (dxv != 0.f || dyv != 0.f)      { cx = dxv; cy = dyv; }
    else if (bx != 0.f || by != 0.f)   { cx = bx;  cy = by;  }
    else                               { cx = 1.f; cy = 0.f; }

    // sin(anglediff(chosen, u)) = cross / |chosen||u|  (wrap-invariant)
    const float dt_ = cx * u.x + cy * u.y;
    const float cr_ = cy * u.x - cx * u.y;
    const float sin_t = cr_ / sqrtf(dt_ * dt_ + cr_ * cr_);

    const float ang = C_ROT * sin_t + (rot_noise[i] * C_RN1) * C_SQDT;
    float sa, ca;
    sincosf(ang, &sa, &ca);
    const float nux = u.x * ca - u.y * sa; // u * exp(i*ang)
    const float nuy = u.x * sa + u.y * ca;

    const float2 tn = trans_noise[i];
    const float tvx = C_TRV * u.x + ((tn.x * C_HALF) * C_SQ2T) * C_SQDT;
    const float tvy = C_TRV * u.y + ((tn.y * C_HALF) * C_SQ2T) * C_SQDT;

    out[1 * NPART + i] = make_float2(nux, nuy);
    out[2 * NPART + i] = make_float2(osx, osy);
    out[3 * NPART + i] = make_float2(Lx, Ly);
    out[4 * NPART + i] = make_float2(Rx, Ry);
    pos0[i] = make_float2(p.x + tvx, p.y + tvy);
}

// ---------------------------------------------------------------------------
// One collision relaxation pass: posB[i] = posA[i] - sum_j move(i,j).
// Same block structure as pair_kernel; 32 KB LDS stage.
// ---------------------------------------------------------------------------
__global__ __launch_bounds__(256) void collide_kernel(
        const float2* __restrict__ posA, float2* __restrict__ posB) {
    __shared__ float2 pl[NPART];          // 32 KB
    float* red = (float*)pl;

    const int tid = threadIdx.x;
    for (int k = 0; k < NPART / 256; ++k) {
        const int j = k * 256 + tid;
        pl[j] = posA[j];
    }
    __syncthreads();

    const int il  = tid & 7;
    const int seg = tid >> 3;
    const float pix = pl[blockIdx.x * 8 + il].x;
    const float piy = pl[blockIdx.x * 8 + il].y;

    float mxx = 0.f, myy = 0.f;
    const int base = seg * 128;
    #pragma unroll 4
    for (int t = 0; t < 128; ++t) {
        const int j = base + ((t + seg) & 127);
        const float2 v = pl[j];
        const float dx = v.x - pix, dy = v.y - piy;
        const float r2 = fmaf(dx, dx, dy * dy);
        if (r2 <= TWORC2 && r2 > 0.f) {   // rare; diagonal excluded via r2>0
            const float ab = sqrtf(r2);
            const float s = (C21RC - ab) * 0.5f / ab;
            mxx = fmaf(dx, s, mxx);
            myy = fmaf(dy, s, myy);
        }
    }
    __syncthreads();
    red[0 * 256 + tid] = mxx;
    red[1 * 256 + tid] = myy;
    __syncthreads();
    if (tid < 8) {
        float ax = 0.f, ay = 0.f;
        #pragma unroll
        for (int s = 0; s < 32; ++s) {
            ax += red[0 * 256 + tid + 8 * s];
            ay += red[1 * 256 + tid + 8 * s];
        }
        // tid<8 => seg==0, il==tid: (pix,piy) is particle blockIdx*8+tid
        posB[blockIdx.x * 8 + tid] = make_float2(pix - ax, piy - ay);
    }
}

extern "C" void kernel_launch(void* const* d_in, const int* in_sizes, int n_in,
                              void* d_out, int out_size, void* d_ws, size_t ws_size,
                              hipStream_t stream) {
    const float2* pos = (const float2*)d_in[0];
    const float2* ori = (const float2*)d_in[1];
    const float*  del = (const float*)d_in[2];
    const float*  rn  = (const float*)d_in[3];
    const float2* tn  = (const float2*)d_in[4];

    float*  ws5 = (float*)d_ws;                                   // 5*N floats
    float2* pA  = (float2*)((char*)d_ws + (size_t)5 * NPART * sizeof(float));
    float2* pB  = pA + NPART;
    float2* o2  = (float2*)d_out;                                 // [5][N] float2

    pair_kernel<<<dim3(512), dim3(256), 0, stream>>>(pos, ori, ws5);
    epilogue_kernel<<<dim3(16), dim3(256), 0, stream>>>(pos, ori, del, rn, tn,
                                                        ws5, o2, pA);
    collide_kernel<<<dim3(512), dim3(256), 0, stream>>>(pA, pB);
    collide_kernel<<<dim3(512), dim3(256), 0, stream>>>(pB, pA);
    collide_kernel<<<dim3(512), dim3(256), 0, stream>>>(pA, o2); // section 0 = new_p
}